// Round 1
// baseline (57011.365 us; speedup 1.0000x reference)
//
#include <hip/hip_runtime.h>
#include <math.h>

#define B 4
#define SEQ 33
#define MAXLEN 32
#define D 640
#define NH 8
#define DH 80
#define NL 6
#define FF 2560
#define V 30000
#define INITLEN 8
#define NBLK 128
#define NT 256
#define NF 32          // FFN chunks
#define CH 80          // FF / NF
#define PRE_P 9        // prefill positions 0..8
#define EOS_TOK 2

struct Par {
  const int* iw;
  const float* emb;
  const float *Wq, *bq, *Wk, *bk, *Wv, *bv, *Wo, *bo;
  const float *ln1s, *ln1b, *W1, *b1, *W2, *b2, *ln2s, *ln2b, *lmW, *lmb;
  int* out;
};

// ---------------- persistent device scratch (write-before-read every call) ---
__device__ float g_Kc[(size_t)NL * B * NH * SEQ * DH];
__device__ float g_Vc[(size_t)NL * B * NH * SEQ * DH];
__device__ float g_xbuf[36 * D];
__device__ float g_h1buf[36 * D];
__device__ float g_pout[36 * NH * D];
__device__ float g_fpart[(size_t)36 * NF * D];
__device__ unsigned long long g_keys[NBLK * B];
__device__ int g_tokens[B * SEQ];

// ---------------- grid barrier (device-scope, XCD-coherent) -----------------
__device__ unsigned g_arrive = 0;
__device__ unsigned g_gen = 0;

__device__ __forceinline__ void gsync() {
  __syncthreads();
  if (threadIdx.x == 0) {
    __threadfence();
    unsigned g = __hip_atomic_load(&g_gen, __ATOMIC_SEQ_CST, __HIP_MEMORY_SCOPE_AGENT);
    unsigned old = __hip_atomic_fetch_add(&g_arrive, 1u, __ATOMIC_SEQ_CST, __HIP_MEMORY_SCOPE_AGENT);
    if (old == NBLK - 1u) {
      __hip_atomic_store(&g_arrive, 0u, __ATOMIC_SEQ_CST, __HIP_MEMORY_SCOPE_AGENT);
      __hip_atomic_fetch_add(&g_gen, 1u, __ATOMIC_SEQ_CST, __HIP_MEMORY_SCOPE_AGENT);
    } else {
      while (__hip_atomic_load(&g_gen, __ATOMIC_RELAXED, __HIP_MEMORY_SCOPE_AGENT) == g) {
        __builtin_amdgcn_s_sleep(2);
      }
    }
    __threadfence();
  }
  __syncthreads();
}

// ---------------- block reduction helpers ------------------------------------
__device__ __forceinline__ float bred_sum(float v, float* s_red) {
  #pragma unroll
  for (int o = 32; o > 0; o >>= 1) v += __shfl_down(v, o, 64);
  __syncthreads();
  if ((threadIdx.x & 63) == 0) s_red[threadIdx.x >> 6] = v;
  __syncthreads();
  return s_red[0] + s_red[1] + s_red[2] + s_red[3];
}

__device__ void ln_inplace(float* row, const float* gam, const float* bet, float* s_red) {
  float ps = 0.f;
  for (int d = threadIdx.x; d < D; d += NT) ps += row[d];
  const float m = bred_sum(ps, s_red) * (1.0f / 640.0f);
  float pv = 0.f;
  for (int d = threadIdx.x; d < D; d += NT) { float t = row[d] - m; pv += t * t; }
  const float var = bred_sum(pv, s_red) * (1.0f / 640.0f);
  const float rstd = 1.0f / sqrtf(var + 1e-6f);
  for (int d = threadIdx.x; d < D; d += NT)
    row[d] = (row[d] - m) * rstd * gam[d] + bet[d];
  __syncthreads();
}

// ---------------- stage A: x-prep + QKV + attention + out-proj partials ------
// blocks 0..31 active: (b,h). P positions starting at p0.
template <int P>
__device__ void stageA(const Par& p, int l, int p0, const int* tokv,
                       float* s_x, float* s_q, float* s_o, float* s_sc, float* s_red)
{
  const int bid = blockIdx.x, tid = threadIdx.x;
  if (bid >= B * NH) return;
  const int b = bid >> 3, h = bid & 7;

  // ---- build layer input x rows into LDS (redundant across the 8 head-blocks)
  for (int i = 0; i < P; ++i) {
    const int r = i * B + b;
    if (l == 0) {
      int t;
      if (P == 1) t = tokv[b];
      else { const int pos = p0 + i; t = (pos == 0) ? 1 : p.iw[b * INITLEN + pos - 1]; }
      const float* e = p.emb + (size_t)t * D;
      for (int d = tid; d < D; d += NT) s_x[i * D + d] = e[d];
      __syncthreads();
    } else {
      const float* b2 = p.b2 + (size_t)(l - 1) * D;
      for (int d = tid; d < D; d += NT) {
        float acc = g_h1buf[r * D + d] + b2[d];
        const float* fp = g_fpart + ((size_t)r * NF) * D + d;
        for (int cc = 0; cc < NF; ++cc) acc += fp[(size_t)cc * D];
        s_x[i * D + d] = acc;
      }
      __syncthreads();
      ln_inplace(s_x + i * D, p.ln2s + (size_t)(l - 1) * D, p.ln2b + (size_t)(l - 1) * D, s_red);
    }
    if (h == 0)
      for (int d = tid; d < D; d += NT) g_xbuf[r * D + d] = s_x[i * D + d];
  }
  __syncthreads();

  // ---- QKV: threads 0..239 -> (matrix, head column)
  {
    const int mat = tid / DH, j = tid % DH;
    if (mat < 3) {
      const int col = h * DH + j;
      const float* W = (mat == 0 ? p.Wq : mat == 1 ? p.Wk : p.Wv) + (size_t)l * D * D + col;
      const float bias = *((mat == 0 ? p.bq : mat == 1 ? p.bk : p.bv) + (size_t)l * D + col);
      float acc[P];
      #pragma unroll
      for (int i = 0; i < P; ++i) acc[i] = 0.f;
      for (int d = 0; d < D; ++d) {
        const float w = W[(size_t)d * D];
        #pragma unroll
        for (int i = 0; i < P; ++i) acc[i] += s_x[i * D + d] * w;
      }
      #pragma unroll
      for (int i = 0; i < P; ++i) {
        const float val = acc[i] + bias;
        const int pos = p0 + i;
        if (mat == 0) s_q[i * DH + j] = val;
        else {
          float* cache = (mat == 1 ? g_Kc : g_Vc) +
                         ((((size_t)l * B + b) * NH + h) * SEQ + pos) * DH + j;
          *cache = val;
        }
      }
    }
  }
  __syncthreads();

  // ---- attention (causal; masked keys are exactly 0 in ref after softmax)
  const float* kbase = g_Kc + ((((size_t)l * B + b) * NH + h) * SEQ) * DH;
  const float* vbase = g_Vc + ((((size_t)l * B + b) * NH + h) * SEQ) * DH;
  for (int i = 0; i < P; ++i) {
    const int ap = p0 + i, nk = ap + 1;
    if (tid < nk) {
      const float* kk = kbase + (size_t)tid * DH;
      float s = 0.f;
      for (int jj = 0; jj < DH; ++jj) s += s_q[i * DH + jj] * kk[jj];
      s_sc[tid] = s / 8.94427190999915878564f;  // sqrt(80)
    }
    __syncthreads();
    if (tid == 0) {
      float m = -1e30f;
      for (int t = 0; t < nk; ++t) m = fmaxf(m, s_sc[t]);
      s_sc[34] = m;
    }
    __syncthreads();
    if (tid < nk) s_sc[tid] = expf(s_sc[tid] - s_sc[34]);
    __syncthreads();
    if (tid == 0) {
      float ssum = 0.f;
      for (int t = 0; t < nk; ++t) ssum += s_sc[t];
      s_sc[35] = 1.0f / ssum;
    }
    __syncthreads();
    if (tid < DH) {
      float acc = 0.f;
      for (int t = 0; t < nk; ++t) acc += s_sc[t] * vbase[(size_t)t * DH + tid];
      s_o[i * DH + tid] = acc * s_sc[35];
    }
    __syncthreads();
  }

  // ---- per-head out-projection partial: o_h @ Wo[h*DH : (h+1)*DH, :]
  {
    const float* Wo = p.Wo + (size_t)l * D * D;
    float acc[3 * P];
    #pragma unroll
    for (int q2 = 0; q2 < 3 * P; ++q2) acc[q2] = 0.f;
    for (int jj = 0; jj < DH; ++jj) {
      const float* wrow = Wo + (size_t)(h * DH + jj) * D;
      #pragma unroll
      for (int s2 = 0; s2 < 3; ++s2) {
        const int col = tid + s2 * NT;
        if (col < D) {
          const float w = wrow[col];
          #pragma unroll
          for (int i = 0; i < P; ++i) acc[s2 * P + i] += s_o[i * DH + jj] * w;
        }
      }
    }
    #pragma unroll
    for (int s2 = 0; s2 < 3; ++s2) {
      const int col = tid + s2 * NT;
      if (col < D) {
        #pragma unroll
        for (int i = 0; i < P; ++i) {
          const int r = i * B + b;
          g_pout[((size_t)r * NH + h) * D + col] = acc[s2 * P + i];
        }
      }
    }
  }
}

// ---------------- stage F: residual+LN1 (redundant), FFN1 chunk, FFN2 partial
// blocks: g = bid/NF handles rows [g*RPG, g*RPG+RPG), cc = bid%NF the f-chunk.
template <int RPG>
__device__ void stageF(const Par& p, int l, int G, float* s_x, float* s_f, float* s_red)
{
  const int bid = blockIdx.x, tid = threadIdx.x;
  if (bid >= G * NF) return;
  const int g = bid / NF, cc = bid % NF;
  const int r0 = g * RPG;

  for (int rr = 0; rr < RPG; ++rr) {
    const int r = r0 + rr;
    const float* bo = p.bo + (size_t)l * D;
    for (int d = tid; d < D; d += NT) {
      float acc = g_xbuf[r * D + d] + bo[d];
      const float* pp = g_pout + (size_t)r * NH * D + d;
      #pragma unroll
      for (int hh = 0; hh < NH; ++hh) acc += pp[(size_t)hh * D];
      s_x[rr * D + d] = acc;
    }
    __syncthreads();
    ln_inplace(s_x + rr * D, p.ln1s + (size_t)l * D, p.ln1b + (size_t)l * D, s_red);
    if (cc == 0)
      for (int d = tid; d < D; d += NT) g_h1buf[r * D + d] = s_x[rr * D + d];
  }
  __syncthreads();

  // f = relu(h1 @ W1[:, chunk] + b1)
  if (tid < CH) {
    const int fj = cc * CH + tid;
    const float* W1 = p.W1 + (size_t)l * D * FF + fj;
    float acc[RPG];
    #pragma unroll
    for (int rr = 0; rr < RPG; ++rr) acc[rr] = 0.f;
    for (int d = 0; d < D; ++d) {
      const float w = W1[(size_t)d * FF];
      #pragma unroll
      for (int rr = 0; rr < RPG; ++rr) acc[rr] += s_x[rr * D + d] * w;
    }
    const float b1v = p.b1[(size_t)l * FF + fj];
    #pragma unroll
    for (int rr = 0; rr < RPG; ++rr) s_f[rr * CH + tid] = fmaxf(acc[rr] + b1v, 0.f);
  }
  __syncthreads();

  // partial2 = f_chunk @ W2[chunk, :]
  {
    const float* W2 = p.W2 + (size_t)l * FF * D;
    float acc[3 * RPG];
    #pragma unroll
    for (int q2 = 0; q2 < 3 * RPG; ++q2) acc[q2] = 0.f;
    for (int jj = 0; jj < CH; ++jj) {
      const float* wrow = W2 + ((size_t)cc * CH + jj) * D;
      #pragma unroll
      for (int s2 = 0; s2 < 3; ++s2) {
        const int col = tid + s2 * NT;
        if (col < D) {
          const float w = wrow[col];
          #pragma unroll
          for (int rr = 0; rr < RPG; ++rr) acc[s2 * RPG + rr] += s_f[rr * CH + jj] * w;
        }
      }
    }
    #pragma unroll
    for (int s2 = 0; s2 < 3; ++s2) {
      const int col = tid + s2 * NT;
      if (col < D) {
        #pragma unroll
        for (int rr = 0; rr < RPG; ++rr)
          g_fpart[(((size_t)(r0 + rr)) * NF + cc) * D + col] = acc[s2 * RPG + rr];
      }
    }
  }
}

// ---------------- LM head: final LN2 (redundant), vocab-chunk logits + argmax
__device__ void stageLM(const Par& p, int rb, float* s_x, float* s_red,
                        unsigned long long* s_k64)
{
  const int bid = blockIdx.x, tid = threadIdx.x;
  const float* b2 = p.b2 + (size_t)(NL - 1) * D;
  for (int b = 0; b < B; ++b) {
    const int r = rb + b;
    for (int d = tid; d < D; d += NT) {
      float acc = g_h1buf[r * D + d] + b2[d];
      const float* fp = g_fpart + ((size_t)r * NF) * D + d;
      for (int cc = 0; cc < NF; ++cc) acc += fp[(size_t)cc * D];
      s_x[b * D + d] = acc;
    }
    __syncthreads();
    ln_inplace(s_x + b * D, p.ln2s + (size_t)(NL - 1) * D, p.ln2b + (size_t)(NL - 1) * D, s_red);
  }

  const int C = (V + NBLK - 1) / NBLK;  // 235
  const int col = bid * C + tid;
  const bool valid = (tid < C) && (col < V);
  float acc[B];
  if (valid) {
    const float lb = p.lmb[col];
    #pragma unroll
    for (int b = 0; b < B; ++b) acc[b] = lb;
    const float* W = p.lmW + col;
    for (int d = 0; d < D; ++d) {
      const float w = W[(size_t)d * V];
      #pragma unroll
      for (int b = 0; b < B; ++b) acc[b] += s_x[b * D + d] * w;
    }
  }
  for (int b = 0; b < B; ++b) {
    unsigned long long key = 0ull;
    if (valid) {
      unsigned u = __float_as_uint(acc[b]);
      u = (u & 0x80000000u) ? ~u : (u | 0x80000000u);
      key = ((unsigned long long)u << 32) | (unsigned)(V - col);  // ties -> lowest idx
    }
    #pragma unroll
    for (int o = 32; o > 0; o >>= 1) {
      unsigned long long o2 = __shfl_down(key, o, 64);
      if (o2 > key) key = o2;
    }
    __syncthreads();
    if ((tid & 63) == 0) s_k64[tid >> 6] = key;
    __syncthreads();
    if (tid == 0) {
      unsigned long long k0 = s_k64[0];
      #pragma unroll
      for (int q2 = 1; q2 < 4; ++q2) if (s_k64[q2] > k0) k0 = s_k64[q2];
      g_keys[(size_t)bid * B + b] = k0;
    }
  }
  __syncthreads();
}

// ---------------- redundant grid-uniform token reduce ------------------------
__device__ void ctl_tokens(int* tok, bool* allEOS, unsigned long long* s_k64, int* s_tok)
{
  const int tid = threadIdx.x;
  for (int b = 0; b < B; ++b) {
    unsigned long long key = 0ull;
    if (tid < NBLK) key = g_keys[(size_t)tid * B + b];
    #pragma unroll
    for (int o = 32; o > 0; o >>= 1) {
      unsigned long long o2 = __shfl_down(key, o, 64);
      if (o2 > key) key = o2;
    }
    __syncthreads();
    if ((tid & 63) == 0) s_k64[tid >> 6] = key;
    __syncthreads();
    if (tid == 0) {
      unsigned long long k0 = s_k64[0];
      #pragma unroll
      for (int q2 = 1; q2 < 4; ++q2) if (s_k64[q2] > k0) k0 = s_k64[q2];
      s_tok[b] = V - (int)(unsigned)(k0 & 0xFFFFFFFFull);
    }
    __syncthreads();
  }
  bool ae = true;
  #pragma unroll
  for (int b = 0; b < B; ++b) { tok[b] = s_tok[b]; ae = ae && (tok[b] == EOS_TOK); }
  *allEOS = ae;
}

// ---------------- main persistent kernel -------------------------------------
__global__ __launch_bounds__(NT) void tfgen(Par p)
{
  __shared__ float s_x[PRE_P * D];
  __shared__ float s_q[PRE_P * DH];
  __shared__ float s_o[PRE_P * DH];
  __shared__ float s_sc[40];
  __shared__ float s_red[8];
  __shared__ unsigned long long s_k64[4];
  __shared__ int s_tok[B];

  const int bid = blockIdx.x, tid = threadIdx.x;

  if (bid == 0) {
    for (int i = tid; i < B * SEQ; i += NT) {
      const int b = i / SEQ, pos = i % SEQ;
      int t = 0;
      if (pos == 0) t = 1;                                 // BOS
      else if (pos <= INITLEN) t = p.iw[b * INITLEN + pos - 1];
      g_tokens[i] = t;
    }
  }

  // ---- prefill positions 0..8
  for (int l = 0; l < NL; ++l) {
    stageA<PRE_P>(p, l, 0, nullptr, s_x, s_q, s_o, s_sc, s_red);
    gsync();
    stageF<PRE_P>(p, l, 4, s_x, s_q, s_red);
    gsync();
  }

  int tok[B];
  bool ae;
  for (int t = INITLEN;; ++t) {                            // t = cl = 8..31
    stageLM(p, (t == INITLEN) ? INITLEN * B : 0, s_x, s_red, s_k64);
    gsync();
    ctl_tokens(tok, &ae, s_k64, s_tok);
    if (bid == 0 && tid == 0) {
      #pragma unroll
      for (int b = 0; b < B; ++b) g_tokens[b * SEQ + t + 1] = tok[b];
    }
    if (t == MAXLEN - 1 || ae) break;
    // ---- decode forward for position t+1
    for (int l = 0; l < NL; ++l) {
      stageA<1>(p, l, t + 1, tok, s_x, s_q, s_o, s_sc, s_red);
      gsync();
      stageF<B>(p, l, 1, s_x, s_q, s_red);
      gsync();
    }
  }

  if (bid == 0) {
    for (int i = tid; i < B * MAXLEN; i += NT) {
      const int b = i >> 5, jj = i & 31;
      p.out[i] = g_tokens[b * SEQ + jj + 1];
    }
  }
}

extern "C" void kernel_launch(void* const* d_in, const int* in_sizes, int n_in,
                              void* d_out, int out_size, void* d_ws, size_t ws_size,
                              hipStream_t stream)
{
  (void)in_sizes; (void)n_in; (void)out_size; (void)d_ws; (void)ws_size;
  Par p;
  p.iw   = (const int*)  d_in[0];
  // d_in[1] = max_length (hard-coded 32, fixed at capture)
  p.emb  = (const float*)d_in[2];
  p.Wq   = (const float*)d_in[3];  p.bq   = (const float*)d_in[4];
  p.Wk   = (const float*)d_in[5];  p.bk   = (const float*)d_in[6];
  p.Wv   = (const float*)d_in[7];  p.bv   = (const float*)d_in[8];
  p.Wo   = (const float*)d_in[9];  p.bo   = (const float*)d_in[10];
  p.ln1s = (const float*)d_in[11]; p.ln1b = (const float*)d_in[12];
  p.W1   = (const float*)d_in[13]; p.b1   = (const float*)d_in[14];
  p.W2   = (const float*)d_in[15]; p.b2   = (const float*)d_in[16];
  p.ln2s = (const float*)d_in[17]; p.ln2b = (const float*)d_in[18];
  p.lmW  = (const float*)d_in[19]; p.lmb  = (const float*)d_in[20];
  p.out  = (int*)d_out;

  void* args[] = { (void*)&p };
  hipError_t err = hipLaunchCooperativeKernel((const void*)tfgen, dim3(NBLK), dim3(NT),
                                              args, 0, stream);
  if (err != hipSuccess) {
    // 128 blocks x 256 threads trivially co-resident on 256 CUs; barrier still safe.
    hipLaunchKernelGGL(tfgen, dim3(NBLK), dim3(NT), 0, stream, p);
  }
}

// Round 2
// 33599.008 us; speedup vs baseline: 1.6968x; 1.6968x over previous
//
#include <hip/hip_runtime.h>
#include <math.h>

#define B 4
#define SEQ 33
#define MAXLEN 32
#define D 640
#define NH 8
#define DH 80
#define NL 6
#define FF 2560
#define V 30000
#define INITLEN 8
#define NBLK 1024
#define NT 256
#define EOS_TOK 2
#define NPOS_P 9
#define NR_P 36
#define LM_NB 938   // ceil(30000/32)

struct Par {
  const int* iw;
  const float* emb;
  const float *Wq, *bq, *Wk, *bk, *Wv, *bv, *Wo, *bo;
  const float *ln1s, *ln1b, *W1, *b1, *W2, *b2, *ln2s, *ln2b, *lmW, *lmb;
  int* out;
};

// ---------------- persistent device scratch ----------------------------------
__device__ float g_Kc[(size_t)NL * B * NH * SEQ * DH];
__device__ float g_Vc[(size_t)NL * B * NH * SEQ * DH];
// decode buffers
__device__ float g_x[B * D];
__device__ float g_h1[B * D];
__device__ float g_qkvp[(size_t)16 * 1920 * B];
__device__ float g_opart[(size_t)NH * D * B];
__device__ float g_f1p[(size_t)16 * FF * B];
__device__ float g_f2p[(size_t)32 * D * B];
// prefill buffers (36 rows)
__device__ float g_xp[NR_P * D];
__device__ float g_h1p[NR_P * D];
__device__ float g_qkvpP[(size_t)8 * 1920 * NR_P];
__device__ float g_qP[(size_t)NH * NR_P * DH];
__device__ float g_opartP[(size_t)NH * D * NR_P];
__device__ float g_f1pP[(size_t)8 * FF * NR_P];
__device__ float g_f2pP[(size_t)32 * D * NR_P];
// control
__device__ unsigned long long g_keys[(size_t)NBLK * B];
__device__ int g_tokens[B * SEQ];
__device__ int g_tok[B];
__device__ int g_stop;
__device__ unsigned g_flags[2048];
__device__ unsigned g_arrive = 0;
__device__ unsigned g_gen = 0;

#define KCIDX(l,b,h,pos,j) (((((size_t)(l)*B+(b))*NH+(h))*SEQ+(pos))*DH+(j))

// ---------------- init-time full grid barrier --------------------------------
__device__ __forceinline__ void gsync_full() {
  __syncthreads();
  if (threadIdx.x == 0) {
    __threadfence();
    unsigned g = __hip_atomic_load(&g_gen, __ATOMIC_SEQ_CST, __HIP_MEMORY_SCOPE_AGENT);
    unsigned old = __hip_atomic_fetch_add(&g_arrive, 1u, __ATOMIC_SEQ_CST, __HIP_MEMORY_SCOPE_AGENT);
    if (old == NBLK - 1u) {
      __hip_atomic_store(&g_arrive, 0u, __ATOMIC_SEQ_CST, __HIP_MEMORY_SCOPE_AGENT);
      __hip_atomic_fetch_add(&g_gen, 1u, __ATOMIC_SEQ_CST, __HIP_MEMORY_SCOPE_AGENT);
    } else {
      while (__hip_atomic_load(&g_gen, __ATOMIC_RELAXED, __HIP_MEMORY_SCOPE_AGENT) == g)
        __builtin_amdgcn_s_sleep(2);
    }
    __threadfence();
  }
  __syncthreads();
}

// ---------------- flag-based stage sync --------------------------------------
__device__ __forceinline__ void stage_done(int idx) {
  __syncthreads();
  if (threadIdx.x == 0) {
    __threadfence();
    __hip_atomic_fetch_add(&g_flags[idx], 1u, __ATOMIC_RELEASE, __HIP_MEMORY_SCOPE_AGENT);
  }
}
__device__ __forceinline__ void stage_wait(int idx, unsigned cnt) {
  if (threadIdx.x == 0) {
    int spins = 0;
    while (__hip_atomic_load(&g_flags[idx], __ATOMIC_RELAXED, __HIP_MEMORY_SCOPE_AGENT) < cnt) {
      if (spins < 64) __builtin_amdgcn_s_sleep(2);
      else            __builtin_amdgcn_s_sleep(16);
      ++spins;
    }
    __threadfence();
  }
  __syncthreads();
}

// ---------------- LN helpers -------------------------------------------------
__device__ __forceinline__ float bred_sum(float v, float* s_red) {
  #pragma unroll
  for (int o = 32; o > 0; o >>= 1) v += __shfl_down(v, o, 64);
  __syncthreads();
  if ((threadIdx.x & 63) == 0) s_red[threadIdx.x >> 6] = v;
  __syncthreads();
  return s_red[0] + s_red[1] + s_red[2] + s_red[3];
}

__device__ void ln_inplace(float* row, const float* gam, const float* bet, float* s_red) {
  float ps = 0.f;
  for (int d = threadIdx.x; d < D; d += NT) ps += row[d];
  const float m = bred_sum(ps, s_red) * (1.0f / 640.0f);
  float pv = 0.f;
  for (int d = threadIdx.x; d < D; d += NT) { float t = row[d] - m; pv += t * t; }
  const float var = bred_sum(pv, s_red) * (1.0f / 640.0f);
  const float rstd = 1.0f / sqrtf(var + 1e-6f);
  for (int d = threadIdx.x; d < D; d += NT)
    row[d] = (row[d] - m) * rstd * gam[d] + bet[d];
  __syncthreads();
}

// =================== DECODE STAGES ===========================================

// Q: blocks [0,128): h=bid>>4, s=bid&15. depth slice [s*40,+40), cols head h q/k/v.
__device__ void st_Q(const Par& p, int l, float* s_xs) {
  const int bid = blockIdx.x, tid = threadIdx.x;
  const int h = bid >> 4, s = bid & 15;
  if (tid < 160) {
    const int b = tid / 40, dd = tid % 40;
    float v;
    if (l == 0) v = p.emb[(size_t)g_tok[b] * D + s * 40 + dd];
    else        v = g_x[b * D + s * 40 + dd];
    s_xs[b * 40 + dd] = v;
    if (l == 0 && h == 0) g_x[b * D + s * 40 + dd] = v;  // publish emb row as layer input
  }
  __syncthreads();
  if (tid < 240) {
    const int m = tid / 80, j = tid % 80, col = h * 80 + j;
    const float* W = (m == 0 ? p.Wq : m == 1 ? p.Wk : p.Wv) + (size_t)l * D * D + col;
    const int d0 = s * 40;
    float a0 = 0, a1 = 0, a2 = 0, a3 = 0;
    for (int dd = 0; dd < 40; ++dd) {
      const float w = W[(size_t)(d0 + dd) * D];
      a0 += s_xs[0 * 40 + dd] * w; a1 += s_xs[1 * 40 + dd] * w;
      a2 += s_xs[2 * 40 + dd] * w; a3 += s_xs[3 * 40 + dd] * w;
    }
    float* o = g_qkvp + ((size_t)s * 1920 + m * 640 + col) * B;
    o[0] = a0; o[1] = a1; o[2] = a2; o[3] = a3;
  }
}

// AW: blocks [128,192): h=(bid-128)>>3, c=(bid-128)&7. pos = current position.
__device__ void st_AW(const Par& p, int l, int pos,
                      float* s_q, float* s_k, float* s_v, float* s_o, float* s_sc, float* s_wo) {
  const int idx = blockIdx.x - 128, h = idx >> 3, c = idx & 7, tid = threadIdx.x;
  // reduce qkv partials
  for (int task = tid; task < 960; task += NT) {
    const int m = task / 320, rem = task % 320, j = rem >> 2, b = rem & 3;
    const int col = m * 640 + h * 80 + j;
    const float* pp = g_qkvp + (size_t)col * B + b;
    float a = 0.f;
    #pragma unroll
    for (int s = 0; s < 16; ++s) a += pp[(size_t)s * 1920 * B];
    a += (m == 0 ? p.bq : m == 1 ? p.bk : p.bv)[(size_t)l * D + h * 80 + j];
    (m == 0 ? s_q : m == 1 ? s_k : s_v)[b * 80 + j] = a;
  }
  __syncthreads();
  if (c == 0) {  // publish new K/V to cache
    for (int task = tid; task < 2 * B * DH; task += NT) {
      const int which = task / 320, rem = task % 320, b = rem / 80, j = rem % 80;
      const float val = (which == 0 ? s_k : s_v)[b * 80 + j];
      float* dst = (which == 0 ? g_Kc : g_Vc) + KCIDX(l, b, h, pos, j);
      *dst = val;
    }
  }
  const int nk = pos + 1;
  // scores
  for (int task = tid; task < 4 * nk; task += NT) {
    const int b = task / nk, kp = task % nk;
    const float* kk = (kp == pos) ? (s_k + b * 80) : (g_Kc + KCIDX(l, b, h, kp, 0));
    const float* qq = s_q + b * 80;
    float sd = 0.f;
    for (int j = 0; j < 80; ++j) sd += qq[j] * kk[j];
    s_sc[b * 33 + kp] = sd / 8.94427190999915878564f;
  }
  __syncthreads();
  if (tid < 4) {
    const int b = tid;
    float m = -1e30f;
    for (int k = 0; k < nk; ++k) m = fmaxf(m, s_sc[b * 33 + k]);
    float sum = 0.f;
    for (int k = 0; k < nk; ++k) { float e = expf(s_sc[b * 33 + k] - m); s_sc[b * 33 + k] = e; sum += e; }
    s_sc[132 + b] = 1.0f / sum;
  }
  __syncthreads();
  // o
  for (int task = tid; task < 320; task += NT) {
    const int b = task / 80, j = task % 80;
    float acc = 0.f;
    for (int kp = 0; kp < nk; ++kp) {
      const float vv = (kp == pos) ? s_v[b * 80 + j] : g_Vc[KCIDX(l, b, h, kp, j)];
      acc += s_sc[b * 33 + kp] * vv;
    }
    s_o[b * 80 + j] = acc * s_sc[132 + b];
  }
  __syncthreads();
  // Wo partial: cols [c*80,+80), depth rows h*80+[0,80) split in 3 subs
  if (tid < 240) {
    const int j = tid % 80, sub = tid / 80;
    const int col = c * 80 + j;
    const int d0 = sub * 27, d1 = (sub == 2) ? 80 : d0 + 27;
    const float* Wo = p.Wo + (size_t)l * D * D + col;
    float a0 = 0, a1 = 0, a2 = 0, a3 = 0;
    for (int dd = d0; dd < d1; ++dd) {
      const float w = Wo[(size_t)(h * 80 + dd) * D];
      a0 += s_o[0 * 80 + dd] * w; a1 += s_o[1 * 80 + dd] * w;
      a2 += s_o[2 * 80 + dd] * w; a3 += s_o[3 * 80 + dd] * w;
    }
    float* t = s_wo + (j * 3 + sub) * 4;
    t[0] = a0; t[1] = a1; t[2] = a2; t[3] = a3;
  }
  __syncthreads();
  if (tid < 80) {
    const int j = tid, col = c * 80 + j;
    #pragma unroll
    for (int b = 0; b < 4; ++b) {
      const float a = s_wo[(j * 3 + 0) * 4 + b] + s_wo[(j * 3 + 1) * 4 + b] + s_wo[(j * 3 + 2) * 4 + b];
      g_opart[((size_t)h * D + col) * B + b] = a;
    }
  }
}

// RF: blocks [192,196): b = bid-192. residual + LN1 -> g_h1
__device__ void st_RF(const Par& p, int l, float* s_row, float* s_red) {
  const int b = blockIdx.x - 192, tid = threadIdx.x;
  for (int col = tid; col < D; col += NT) {
    float a = g_x[b * D + col] + p.bo[(size_t)l * D + col];
    #pragma unroll
    for (int h = 0; h < 8; ++h) a += g_opart[((size_t)h * D + col) * B + b];
    s_row[col] = a;
  }
  __syncthreads();
  ln_inplace(s_row, p.ln1s + (size_t)l * D, p.ln1b + (size_t)l * D, s_red);
  for (int col = tid; col < D; col += NT) g_h1[b * D + col] = s_row[col];
}

// F1: blocks [196,356): s=idx/10 in [0,16), cg=idx%10. FFN1 partials.
__device__ void st_F1(const Par& p, int l, float* s_xs) {
  const int idx = blockIdx.x - 196, s = idx / 10, cg = idx % 10, tid = threadIdx.x;
  if (tid < 160) {
    const int b = tid / 40, dd = tid % 40;
    s_xs[b * 40 + dd] = g_h1[b * D + s * 40 + dd];
  }
  __syncthreads();
  const int col = cg * 256 + tid;
  const float* W = p.W1 + (size_t)l * D * FF + col;
  float a0 = 0, a1 = 0, a2 = 0, a3 = 0;
  for (int dd = 0; dd < 40; ++dd) {
    const float w = W[(size_t)(s * 40 + dd) * FF];
    a0 += s_xs[0 * 40 + dd] * w; a1 += s_xs[1 * 40 + dd] * w;
    a2 += s_xs[2 * 40 + dd] * w; a3 += s_xs[3 * 40 + dd] * w;
  }
  float* o = g_f1p + ((size_t)s * FF + col) * B;
  o[0] = a0; o[1] = a1; o[2] = a2; o[3] = a3;
}

// F2: blocks [356,484): c=idx>>2 in [0,32), g=idx&3. reduce+relu then W2 slice.
__device__ void st_F2(const Par& p, int l, float* s_f) {
  const int idx = blockIdx.x - 356, c = idx >> 2, g = idx & 3, tid = threadIdx.x;
  for (int task = tid; task < 320; task += NT) {
    const int fj = task >> 2, b = task & 3;
    const int fcol = c * 80 + fj;
    const float* pp = g_f1p + (size_t)fcol * B + b;
    float a = 0.f;
    #pragma unroll
    for (int s = 0; s < 16; ++s) a += pp[(size_t)s * FF * B];
    a += p.b1[(size_t)l * FF + fcol];
    s_f[fj * 4 + b] = fmaxf(a, 0.f);
  }
  __syncthreads();
  if (tid < 160) {
    const int col = g * 160 + tid;
    const float* W = p.W2 + (size_t)l * FF * D + col;
    float a0 = 0, a1 = 0, a2 = 0, a3 = 0;
    for (int fj = 0; fj < 80; ++fj) {
      const float w = W[(size_t)(c * 80 + fj) * D];
      a0 += s_f[fj * 4 + 0] * w; a1 += s_f[fj * 4 + 1] * w;
      a2 += s_f[fj * 4 + 2] * w; a3 += s_f[fj * 4 + 3] * w;
    }
    float* o = g_f2p + ((size_t)c * D + col) * B;
    o[0] = a0; o[1] = a1; o[2] = a2; o[3] = a3;
  }
}

// RQ / RL: blocks [484,488): b. residual + LN2(lprev) -> g_x
__device__ void st_RQ(const Par& p, int lprev, float* s_row, float* s_red) {
  const int b = blockIdx.x - 484, tid = threadIdx.x;
  for (int col = tid; col < D; col += NT) {
    float a = g_h1[b * D + col] + p.b2[(size_t)lprev * D + col];
    #pragma unroll 8
    for (int c = 0; c < 32; ++c) a += g_f2p[((size_t)c * D + col) * B + b];
    s_row[col] = a;
  }
  __syncthreads();
  ln_inplace(s_row, p.ln2s + (size_t)lprev * D, p.ln2b + (size_t)lprev * D, s_red);
  for (int col = tid; col < D; col += NT) g_x[b * D + col] = s_row[col];
}

// LM: blocks [0,938): 32 cols each, depth split 8x80.
__device__ void st_LM(const Par& p, float* s_xf, float* s_part, unsigned long long* s_key) {
  const int bid = blockIdx.x, tid = threadIdx.x;
  for (int i = tid; i < B * D; i += NT) s_xf[i] = g_x[i];
  __syncthreads();
  const int sg = tid >> 5, cj = tid & 31;
  const int col = bid * 32 + cj;
  float a0 = 0, a1 = 0, a2 = 0, a3 = 0;
  if (col < V) {
    const float* W = p.lmW + (size_t)sg * 80 * V + col;
    for (int dd = 0; dd < 80; ++dd) {
      const float w = W[(size_t)dd * V];
      const int d = sg * 80 + dd;
      a0 += s_xf[0 * D + d] * w; a1 += s_xf[1 * D + d] * w;
      a2 += s_xf[2 * D + d] * w; a3 += s_xf[3 * D + d] * w;
    }
  }
  float* t = s_part + (sg * 32 + cj) * 4;
  t[0] = a0; t[1] = a1; t[2] = a2; t[3] = a3;
  __syncthreads();
  if (tid < 128) {
    const int cj2 = tid >> 2, b = tid & 3, col2 = bid * 32 + cj2;
    unsigned long long key = 0ull;
    if (col2 < V) {
      float a = p.lmb[col2];
      #pragma unroll
      for (int sg2 = 0; sg2 < 8; ++sg2) a += s_part[(sg2 * 32 + cj2) * 4 + b];
      unsigned u = __float_as_uint(a);
      u = (u & 0x80000000u) ? ~u : (u | 0x80000000u);
      key = ((unsigned long long)u << 32) | (unsigned)(V - col2);
    }
    s_key[cj2 * 4 + b] = key;
  }
  __syncthreads();
  if (tid < 4) {
    unsigned long long k0 = 0ull;
    for (int cj2 = 0; cj2 < 32; ++cj2) {
      const unsigned long long k = s_key[cj2 * 4 + tid];
      if (k > k0) k0 = k;
    }
    g_keys[(size_t)bid * B + tid] = k0;
  }
}

// CTL: block 1023
__device__ void st_CTL(int t, unsigned long long* s_k64) {
  const int tid = threadIdx.x;
  for (int b = 0; b < B; ++b) {
    unsigned long long k = 0ull;
    for (int i = tid; i < LM_NB; i += NT) {
      const unsigned long long kk = g_keys[(size_t)i * B + b];
      if (kk > k) k = kk;
    }
    #pragma unroll
    for (int o = 32; o > 0; o >>= 1) {
      const unsigned long long kk = __shfl_down(k, o, 64);
      if (kk > k) k = kk;
    }
    __syncthreads();
    if ((tid & 63) == 0) s_k64[tid >> 6] = k;
    __syncthreads();
    if (tid == 0) {
      unsigned long long k0 = s_k64[0];
      #pragma unroll
      for (int q = 1; q < 4; ++q) if (s_k64[q] > k0) k0 = s_k64[q];
      const int tok = V - (int)(unsigned)(k0 & 0xFFFFFFFFull);
      g_tok[b] = tok;
      g_tokens[b * SEQ + t + 1] = tok;
    }
    __syncthreads();
  }
  if (tid == 0) {
    int stop = (t == MAXLEN - 1) ? 1 : 0;
    bool ae = true;
    for (int b = 0; b < B; ++b) ae = ae && (g_tok[b] == EOS_TOK);
    if (ae) stop = 1;
    g_stop = stop;
  }
}

// =================== PREFILL STAGES (36 rows) ================================

// Qp: blocks [0,192): h=idx/24, s=(idx%24)/3 in [0,8), rg=idx%3. 12 rows, depth 80.
__device__ void st_Qp(const Par& p, int l, float* s_a) {
  const int idx = blockIdx.x, tid = threadIdx.x;
  const int h = idx / 24, rem = idx % 24, s = rem / 3, rg = rem % 3;
  const int r0 = rg * 12, d0 = s * 80;
  for (int i = tid; i < 960; i += NT) {
    const int ri = i / 80, dd = i % 80;
    s_a[i] = g_xp[(r0 + ri) * D + d0 + dd];
  }
  __syncthreads();
  if (tid < 240) {
    const int m = tid / 80, j = tid % 80, col = h * 80 + j;
    const float* W = (m == 0 ? p.Wq : m == 1 ? p.Wk : p.Wv) + (size_t)l * D * D + col;
    float acc[12];
    #pragma unroll
    for (int ri = 0; ri < 12; ++ri) acc[ri] = 0.f;
    for (int dd = 0; dd < 80; ++dd) {
      const float w = W[(size_t)(d0 + dd) * D];
      #pragma unroll
      for (int ri = 0; ri < 12; ++ri) acc[ri] += s_a[ri * 80 + dd] * w;
    }
    float* o = g_qkvpP + ((size_t)s * 1920 + m * 640 + col) * NR_P + r0;
    #pragma unroll
    for (int ri = 0; ri < 12; ++ri) o[ri] = acc[ri];
  }
}

// AWp1: blocks [192,224): h=idx>>2, c=idx&3: positions {c, c+4, c+8}. reduce -> q global, K/V cache.
__device__ void st_AWp1(const Par& p, int l) {
  const int idx = blockIdx.x - 192, h = idx >> 2, c = idx & 3, tid = threadIdx.x;
  for (int pp = c; pp < NPOS_P; pp += 4) {
    for (int task = tid; task < 960; task += NT) {
      const int m = task / 320, rem = task % 320, j = rem >> 2, b = rem & 3;
      const int r = pp * 4 + b;
      const int col = m * 640 + h * 80 + j;
      const float* q = g_qkvpP + (size_t)col * NR_P + r;
      float a = 0.f;
      #pragma unroll
      for (int s = 0; s < 8; ++s) a += q[(size_t)s * 1920 * NR_P];
      a += (m == 0 ? p.bq : m == 1 ? p.bk : p.bv)[(size_t)l * D + h * 80 + j];
      if (m == 0)      g_qP[((size_t)h * NR_P + r) * DH + j] = a;
      else if (m == 1) g_Kc[KCIDX(l, b, h, pp, j)] = a;
      else             g_Vc[KCIDX(l, b, h, pp, j)] = a;
    }
  }
}

// AWp2: blocks [224,256): h=idx>>2, rg=idx&3: rows [rg*9, rg*9+9). attn + Wo.
__device__ void st_AWp2(const Par& p, int l, float* s_a, float* s_b, float* s_c) {
  const int idx = blockIdx.x - 224, h = idx >> 2, rg = idx & 3, tid = threadIdx.x;
  const int r0 = rg * 9;
  for (int i = tid; i < 720; i += NT) {
    const int ri = i / 80, j = i % 80;
    s_a[i] = g_qP[((size_t)h * NR_P + r0 + ri) * DH + j];
  }
  __syncthreads();
  for (int task = tid; task < 81; task += NT) {
    const int ri = task / 9, kp = task % 9;
    const int r = r0 + ri, pos = r >> 2, b = r & 3;
    if (kp <= pos) {
      const float* kk = g_Kc + KCIDX(l, b, h, kp, 0);
      const float* qq = s_a + ri * 80;
      float sd = 0.f;
      for (int j = 0; j < 80; ++j) sd += qq[j] * kk[j];
      s_c[ri * 9 + kp] = sd / 8.94427190999915878564f;
    }
  }
  __syncthreads();
  if (tid < 9) {
    const int ri = tid, r = r0 + ri, pos = r >> 2;
    float m = -1e30f;
    for (int k = 0; k <= pos; ++k) m = fmaxf(m, s_c[ri * 9 + k]);
    float sum = 0.f;
    for (int k = 0; k <= pos; ++k) { float e = expf(s_c[ri * 9 + k] - m); s_c[ri * 9 + k] = e; sum += e; }
    s_c[81 + ri] = 1.0f / sum;
  }
  __syncthreads();
  for (int task = tid; task < 720; task += NT) {
    const int ri = task / 80, j = task % 80;
    const int r = r0 + ri, pos = r >> 2, b = r & 3;
    float acc = 0.f;
    for (int kp = 0; kp <= pos; ++kp)
      acc += s_c[ri * 9 + kp] * g_Vc[KCIDX(l, b, h, kp, j)];
    s_b[ri * 80 + j] = acc * s_c[81 + ri];
  }
  __syncthreads();
  if (tid < 160) {
    for (int pass = 0; pass < 4; ++pass) {
      const int col = pass * 160 + tid;
      const float* Wo = p.Wo + (size_t)l * D * D + col;
      float acc[9];
      #pragma unroll
      for (int ri = 0; ri < 9; ++ri) acc[ri] = 0.f;
      for (int dd = 0; dd < 80; ++dd) {
        const float w = Wo[(size_t)(h * 80 + dd) * D];
        #pragma unroll
        for (int ri = 0; ri < 9; ++ri) acc[ri] += s_b[ri * 80 + dd] * w;
      }
      #pragma unroll
      for (int ri = 0; ri < 9; ++ri)
        g_opartP[((size_t)h * D + col) * NR_P + r0 + ri] = acc[ri];
    }
  }
}

// RFp: blocks [0,36): r. residual + LN1 -> g_h1p
__device__ void st_RFp(const Par& p, int l, float* s_row, float* s_red) {
  const int r = blockIdx.x, tid = threadIdx.x;
  for (int col = tid; col < D; col += NT) {
    float a = g_xp[r * D + col] + p.bo[(size_t)l * D + col];
    #pragma unroll
    for (int h = 0; h < 8; ++h) a += g_opartP[((size_t)h * D + col) * NR_P + r];
    s_row[col] = a;
  }
  __syncthreads();
  ln_inplace(s_row, p.ln1s + (size_t)l * D, p.ln1b + (size_t)l * D, s_red);
  for (int col = tid; col < D; col += NT) g_h1p[r * D + col] = s_row[col];
}

// F1p: blocks [0,240): s=idx/30 in [0,8), cg=(idx%30)/3 in [0,10), rg=idx%3.
__device__ void st_F1p(const Par& p, int l, float* s_a) {
  const int idx = blockIdx.x, tid = threadIdx.x;
  const int s = idx / 30, rem = idx % 30, cg = rem / 3, rg = rem % 3;
  const int r0 = rg * 12, d0 = s * 80;
  for (int i = tid; i < 960; i += NT) {
    const int ri = i / 80, dd = i % 80;
    s_a[i] = g_h1p[(r0 + ri) * D + d0 + dd];
  }
  __syncthreads();
  const int col = cg * 256 + tid;
  const float* W = p.W1 + (size_t)l * D * FF + col;
  float acc[12];
  #pragma unroll
  for (int ri = 0; ri < 12; ++ri) acc[ri] = 0.f;
  for (int dd = 0; dd < 80; ++dd) {
    const float w = W[(size_t)(d0 + dd) * FF];
    #pragma unroll
    for (int ri = 0; ri < 12; ++ri) acc[ri] += s_a[ri * 80 + dd] * w;
  }
  float* o = g_f1pP + ((size_t)s * FF + col) * NR_P + r0;
  #pragma unroll
  for (int ri = 0; ri < 12; ++ri) o[ri] = acc[ri];
}

// F2p: blocks [240,336): c=idx/3 in [0,32), rg=idx%3.
__device__ void st_F2p(const Par& p, int l, float* s_c) {
  const int idx = blockIdx.x - 240, c = idx / 3, rg = idx % 3, tid = threadIdx.x;
  const int r0 = rg * 12;
  for (int task = tid; task < 960; task += NT) {
    const int ri = task / 80, fj = task % 80;
    const int fcol = c * 80 + fj;
    const float* pp = g_f1pP + (size_t)fcol * NR_P + r0 + ri;
    float a = 0.f;
    #pragma unroll
    for (int s = 0; s < 8; ++s) a += pp[(size_t)s * FF * NR_P];
    a += p.b1[(size_t)l * FF + fcol];
    s_c[ri * 80 + fj] = fmaxf(a, 0.f);
  }
  __syncthreads();
  for (int pass = 0; pass < 3; ++pass) {
    const int col = pass * 256 + tid;
    if (col < D) {
      const float* W = p.W2 + (size_t)l * FF * D + col;
      float acc[12];
      #pragma unroll
      for (int ri = 0; ri < 12; ++ri) acc[ri] = 0.f;
      for (int fj = 0; fj < 80; ++fj) {
        const float w = W[(size_t)(c * 80 + fj) * D];
        #pragma unroll
        for (int ri = 0; ri < 12; ++ri) acc[ri] += s_c[ri * 80 + fj] * w;
      }
      float* o = g_f2pP + ((size_t)c * D + col) * NR_P + r0;
      #pragma unroll
      for (int ri = 0; ri < 12; ++ri) o[ri] = acc[ri];
    }
  }
}

// RQp: blocks [0,36): r. residual + LN2 -> g_xp
__device__ void st_RQp(const Par& p, int l, float* s_row, float* s_red) {
  const int r = blockIdx.x, tid = threadIdx.x;
  for (int col = tid; col < D; col += NT) {
    float a = g_h1p[r * D + col] + p.b2[(size_t)l * D + col];
    #pragma unroll 8
    for (int c = 0; c < 32; ++c) a += g_f2pP[((size_t)c * D + col) * NR_P + r];
    s_row[col] = a;
  }
  __syncthreads();
  ln_inplace(s_row, p.ln2s + (size_t)l * D, p.ln2b + (size_t)l * D, s_red);
  for (int col = tid; col < D; col += NT) g_xp[r * D + col] = s_row[col];
}

// RLp: blocks [0,4): b -> rows 32+b (position 8). residual + LN2(5) -> g_x
__device__ void st_RLp(const Par& p, float* s_row, float* s_red) {
  const int b = blockIdx.x, r = 32 + b, tid = threadIdx.x;
  for (int col = tid; col < D; col += NT) {
    float a = g_h1p[r * D + col] + p.b2[(size_t)(NL - 1) * D + col];
    #pragma unroll 8
    for (int c = 0; c < 32; ++c) a += g_f2pP[((size_t)c * D + col) * NR_P + r];
    s_row[col] = a;
  }
  __syncthreads();
  ln_inplace(s_row, p.ln2s + (size_t)(NL - 1) * D, p.ln2b + (size_t)(NL - 1) * D, s_red);
  for (int col = tid; col < D; col += NT) g_x[b * D + col] = s_row[col];
}

// =================== MAIN ====================================================
__global__ __launch_bounds__(NT, 4) void tfgen(Par p) {
  __shared__ float s_x[2560];
  __shared__ float s_a[1024];
  __shared__ float s_b[768];
  __shared__ float s_c[1024];
  __shared__ float s_wo[960];
  __shared__ float s_red[4];
  __shared__ unsigned long long s_key[128];
  __shared__ int s_ctl[4];

  const int bid = blockIdx.x, tid = threadIdx.x;
  int ep = 0;

  // ---- INIT: zero flags, prefill embeddings, token buffer
  if (tid < 2) g_flags[bid * 2 + tid] = 0u;
  if (bid < NR_P) {
    const int pos = bid >> 2, b = bid & 3;
    const int tk = (pos == 0) ? 1 : p.iw[b * INITLEN + pos - 1];
    for (int d = tid; d < D; d += NT) g_xp[bid * D + d] = p.emb[(size_t)tk * D + d];
  }
  if (bid == NBLK - 1) {
    for (int i = tid; i < B * SEQ; i += NT) {
      const int b = i / SEQ, pos = i % SEQ;
      int tk = 0;
      if (pos == 0) tk = 1;
      else if (pos <= INITLEN) tk = p.iw[b * INITLEN + pos - 1];
      g_tokens[i] = tk;
    }
  }
  gsync_full();

  // ---- PREFILL
  int eRQ = -1, eF2last = -1;
  for (int l = 0; l < NL; ++l) {
    const int eQ = ep++;
    if (bid < 192) { if (l > 0) stage_wait(eRQ, 36); st_Qp(p, l, s_a); stage_done(eQ); }
    const int eA1 = ep++;
    if (bid >= 192 && bid < 224) { stage_wait(eQ, 192); st_AWp1(p, l); stage_done(eA1); }
    const int eA2 = ep++;
    if (bid >= 224 && bid < 256) { stage_wait(eA1, 32); st_AWp2(p, l, s_a, s_b, s_c); stage_done(eA2); }
    const int eRF = ep++;
    if (bid < NR_P) { stage_wait(eA2, 32); st_RFp(p, l, s_x, s_red); stage_done(eRF); }
    const int eF1 = ep++;
    if (bid < 240) { stage_wait(eRF, 36); st_F1p(p, l, s_a); stage_done(eF1); }
    const int eF2 = ep++;
    if (bid >= 240 && bid < 336) { stage_wait(eF1, 240); st_F2p(p, l, s_c); stage_done(eF2); }
    eF2last = eF2;
    if (l < NL - 1) {
      eRQ = ep++;
      if (bid < NR_P) { stage_wait(eF2, 96); st_RQp(p, l, s_x, s_red); stage_done(eRQ); }
    }
  }

  // ---- DECODE
  int eCTL = -1;
  for (int t = INITLEN;; ++t) {
    if (t == INITLEN) {
      const int eRL = ep++;
      if (bid < 4) { stage_wait(eF2last, 96); st_RLp(p, s_x, s_red); stage_done(eRL); }
      const int eLM = ep++;
      if (bid < LM_NB) { stage_wait(eRL, 4); st_LM(p, s_x, s_a, s_key); stage_done(eLM); }
      eCTL = ep++;
      if (bid == NBLK - 1) { stage_wait(eLM, LM_NB); st_CTL(t, (unsigned long long*)s_key); stage_done(eCTL); }
    } else {
      int eSrc = -1;  // RQ flag of current layer input
      int eF2d = -1;
      for (int l = 0; l < NL; ++l) {
        const int eQ = ep++;
        if (bid < 128) { if (l > 0) stage_wait(eSrc, 4); st_Q(p, l, s_a); stage_done(eQ); }
        const int eAW = ep++;
        if (bid >= 128 && bid < 192) {
          stage_wait(eQ, 128);
          st_AW(p, l, t, s_a, s_a + 320, s_a + 640, s_b, s_c, s_wo);
          stage_done(eAW);
        }
        const int eRF = ep++;
        if (bid >= 192 && bid < 196) { stage_wait(eAW, 64); st_RF(p, l, s_x, s_red); stage_done(eRF); }
        const int eF1 = ep++;
        if (bid >= 196 && bid < 356) { stage_wait(eRF, 4); st_F1(p, l, s_a); stage_done(eF1); }
        eF2d = ep++;
        if (bid >= 356 && bid < 484) { stage_wait(eF1, 160); st_F2(p, l, s_c); stage_done(eF2d); }
        if (l < NL - 1) {
          eSrc = ep++;
          if (bid >= 484 && bid < 488) { stage_wait(eF2d, 128); st_RQ(p, l, s_x, s_red); stage_done(eSrc); }
        }
      }
      const int eRL = ep++;
      if (bid >= 484 && bid < 488) { stage_wait(eF2d, 128); st_RQ(p, NL - 1, s_x, s_red); stage_done(eRL); }
      const int eLM = ep++;
      if (bid < LM_NB) { stage_wait(eRL, 4); st_LM(p, s_x, s_a, s_key); stage_done(eLM); }
      eCTL = ep++;
      if (bid == NBLK - 1) { stage_wait(eLM, LM_NB); st_CTL(t, (unsigned long long*)s_key); stage_done(eCTL); }
    }
    // all blocks learn the verdict
    stage_wait(eCTL, 1);
    if (tid == 0) s_ctl[0] = g_stop;
    __syncthreads();
    if (s_ctl[0]) break;
  }

  if (bid == 0) {
    for (int i = tid; i < B * MAXLEN; i += NT) {
      const int b = i >> 5, j = i & 31;
      p.out[i] = g_tokens[b * SEQ + j + 1];
    }
  }
}

extern "C" void kernel_launch(void* const* d_in, const int* in_sizes, int n_in,
                              void* d_out, int out_size, void* d_ws, size_t ws_size,
                              hipStream_t stream)
{
  (void)in_sizes; (void)n_in; (void)out_size; (void)d_ws; (void)ws_size;
  Par p;
  p.iw   = (const int*)  d_in[0];
  p.emb  = (const float*)d_in[2];
  p.Wq   = (const float*)d_in[3];  p.bq   = (const float*)d_in[4];
  p.Wk   = (const float*)d_in[5];  p.bk   = (const float*)d_in[6];
  p.Wv   = (const float*)d_in[7];  p.bv   = (const float*)d_in[8];
  p.Wo   = (const float*)d_in[9];  p.bo   = (const float*)d_in[10];
  p.ln1s = (const float*)d_in[11]; p.ln1b = (const float*)d_in[12];
  p.W1   = (const float*)d_in[13]; p.b1   = (const float*)d_in[14];
  p.W2   = (const float*)d_in[15]; p.b2   = (const float*)d_in[16];
  p.ln2s = (const float*)d_in[17]; p.ln2b = (const float*)d_in[18];
  p.lmW  = (const float*)d_in[19]; p.lmb  = (const float*)d_in[20];
  p.out  = (int*)d_out;

  void* args[] = { (void*)&p };
  hipError_t err = hipLaunchCooperativeKernel((const void*)tfgen, dim3(NBLK), dim3(NT),
                                              args, 0, stream);
  if (err != hipSuccess) {
    // __launch_bounds__(256,4) guarantees 4 blocks/CU co-residency on 256 CUs.
    hipLaunchKernelGGL(tfgen, dim3(NBLK), dim3(NT), 0, stream, p);
  }
}